// Round 1
// baseline (471.548 us; speedup 1.0000x reference)
//
#include <hip/hip_runtime.h>
#include <hip/hip_bf16.h>

#define NN 100000
#define EE 1000000
#define H_DIM 124
#define HIDDEN 256
#define PCOLS 512
#define LDK 136   // 128 + 8 bf16 pad: dword stride 68 = 4 mod 32 -> conflict-free b128, 16B aligned

typedef float f32x4 __attribute__((ext_vector_type(4)));
typedef short bf16x8 __attribute__((ext_vector_type(8)));

__device__ __forceinline__ unsigned short f2bf(float f) {
    unsigned int x = __float_as_uint(f);
    unsigned int r = (x + 0x7FFFu + ((x >> 16) & 1u)) >> 16;
    return (unsigned short)r;
}

struct alignas(8) h4 { _Float16 v[4]; };

// ---------------- Kernel 1: build F (bf16 [N,128]) and W1T (bf16 [512,128]) ----------------
__global__ __launch_bounds__(256) void build_tables(const float* __restrict__ h,
                                                    const float* __restrict__ cls,
                                                    const float* __restrict__ W1,
                                                    unsigned short* __restrict__ F,
                                                    unsigned short* __restrict__ W1T) {
    int tid = blockIdx.x * 256 + threadIdx.x;
    if (tid < NN * 128) {
        int n = tid >> 7, j = tid & 127;
        float v;
        if (j < H_DIM) {
            v = h[n * H_DIM + j];
        } else {
            const float* c = cls + n * 4;
            float c0 = c[0], c1 = c[1], c2 = c[2], c3 = c[3];
            float m = fmaxf(fmaxf(c0, c1), fmaxf(c2, c3));
            float e0 = __expf(c0 - m), e1 = __expf(c1 - m), e2 = __expf(c2 - m), e3 = __expf(c3 - m);
            float s = e0 + e1 + e2 + e3;
            int jj = j - H_DIM;
            float ev = (jj == 0) ? e0 : (jj == 1) ? e1 : (jj == 2) ? e2 : e3;
            v = ev / s;
        }
        F[tid] = f2bf(v);
    } else if (tid < NN * 128 + PCOLS * 128) {
        int t2 = tid - NN * 128;
        int j = t2 >> 7, k = t2 & 127;           // j: output col of W1cat (0..511), k: input row (0..127)
        int row = (j < 256) ? k : (130 + k);
        int col = (j < 256) ? j : (j - 256);
        W1T[t2] = f2bf(W1[row * 256 + col]);
    }
}

// ---------------- Kernel 2: P = F @ W1cat, [N,128]x[128,512] -> fp16 P [N,512] ----------------
__global__ __launch_bounds__(256) void p_gemm(const unsigned short* __restrict__ F,
                                              const unsigned short* __restrict__ W1T,
                                              _Float16* __restrict__ P) {
    __shared__ unsigned short As[64 * LDK];
    __shared__ unsigned short Bs[128 * LDK];
    const int m0 = blockIdx.x * 64;
    const int n0 = blockIdx.y * 128;
    const int t = threadIdx.x;

    // Stage A tile: 64 rows x 128 bf16 (16B chunks)
    #pragma unroll
    for (int it = 0; it < 4; ++it) {
        int chunk = t + it * 256;
        int r = chunk >> 4, c = chunk & 15;
        float4 v = make_float4(0.f, 0.f, 0.f, 0.f);
        int row = m0 + r;
        if (row < NN) v = *(const float4*)(F + row * 128 + c * 8);
        *(float4*)(&As[r * LDK + c * 8]) = v;
    }
    // Stage B tile (transposed W1cat): 128 rows x 128 bf16
    #pragma unroll
    for (int it = 0; it < 8; ++it) {
        int chunk = t + it * 256;
        int r = chunk >> 4, c = chunk & 15;
        float4 v = *(const float4*)(W1T + (n0 + r) * 128 + c * 8);
        *(float4*)(&Bs[r * LDK + c * 8]) = v;
    }
    __syncthreads();

    const int wave = t >> 6, lane = t & 63;
    const int wm = wave & 1, wn = wave >> 1;     // 2x2 wave grid: wave covers 32 rows x 64 cols
    const int lm = lane & 15, quad = lane >> 4;

    f32x4 acc[2][4];
    #pragma unroll
    for (int mt = 0; mt < 2; ++mt)
        #pragma unroll
        for (int nt = 0; nt < 4; ++nt)
            acc[mt][nt] = (f32x4){0.f, 0.f, 0.f, 0.f};

    #pragma unroll
    for (int s = 0; s < 4; ++s) {
        int k0 = s * 32 + quad * 8;
        bf16x8 a[2], b[4];
        #pragma unroll
        for (int mt = 0; mt < 2; ++mt)
            a[mt] = *(const bf16x8*)(&As[(wm * 32 + mt * 16 + lm) * LDK + k0]);
        #pragma unroll
        for (int nt = 0; nt < 4; ++nt)
            b[nt] = *(const bf16x8*)(&Bs[(wn * 64 + nt * 16 + lm) * LDK + k0]);
        #pragma unroll
        for (int mt = 0; mt < 2; ++mt)
            #pragma unroll
            for (int nt = 0; nt < 4; ++nt)
                acc[mt][nt] = __builtin_amdgcn_mfma_f32_16x16x32_bf16(a[mt], b[nt], acc[mt][nt], 0, 0, 0);
    }

    // C/D layout (16x16x32): col = lane&15, row = quad*4 + reg
    #pragma unroll
    for (int mt = 0; mt < 2; ++mt) {
        #pragma unroll
        for (int nt = 0; nt < 4; ++nt) {
            int col = n0 + wn * 64 + nt * 16 + lm;
            #pragma unroll
            for (int r = 0; r < 4; ++r) {
                int row = m0 + wm * 32 + mt * 16 + quad * 4 + r;
                if (row < NN) P[(size_t)row * PCOLS + col] = (_Float16)acc[mt][nt][r];
            }
        }
    }
}

// ---------------- Kernel 3: per-edge gather + LN + ReLU + W2 ----------------
#define K3_BLOCKS 2048
#define WAVES_TOTAL (K3_BLOCKS * 4)

__global__ __launch_bounds__(256) void edge_kernel(const _Float16* __restrict__ P,
                                                   const int* __restrict__ src,
                                                   const int* __restrict__ dst,
                                                   const float* __restrict__ polar,
                                                   const float* __restrict__ W1,
                                                   const float* __restrict__ b1,
                                                   const float* __restrict__ gamma,
                                                   const float* __restrict__ beta,
                                                   const float* __restrict__ W2,
                                                   const float* __restrict__ b2,
                                                   float* __restrict__ out) {
    const int lane = threadIdx.x & 63;
    const int wgid = blockIdx.x * 4 + (threadIdx.x >> 6);
    const int j0 = lane * 4;

    float w1p0[4], w1p1[4], b1v[4], gv[4], bv[4], w2a[4], w2b[4];
    #pragma unroll
    for (int i = 0; i < 4; ++i) {
        int j = j0 + i;
        w1p0[i] = W1[128 * 256 + j];
        w1p1[i] = W1[129 * 256 + j];
        b1v[i]  = b1[j];
        gv[i]   = gamma[j];
        bv[i]   = beta[j];
        w2a[i]  = W2[j * 2];
        w2b[i]  = W2[j * 2 + 1];
    }
    const float b20 = b2[0], b21 = b2[1];

    for (int e = wgid; e < EE; e += WAVES_TOTAL) {
        int s = src[e], d = dst[e];
        float p0 = polar[2 * e], p1 = polar[2 * e + 1];
        h4 ps = *(const h4*)(P + (size_t)s * PCOLS + j0);
        h4 pd = *(const h4*)(P + (size_t)d * PCOLS + 256 + j0);

        float z[4], sum = 0.f, ss = 0.f;
        #pragma unroll
        for (int i = 0; i < 4; ++i) {
            z[i] = (float)ps.v[i] + (float)pd.v[i] + p0 * w1p0[i] + p1 * w1p1[i] + b1v[i];
            sum += z[i];
            ss  += z[i] * z[i];
        }
        #pragma unroll
        for (int off = 32; off; off >>= 1) {
            sum += __shfl_xor(sum, off);
            ss  += __shfl_xor(ss, off);
        }
        float mu   = sum * (1.0f / 256.0f);
        float var  = ss * (1.0f / 256.0f) - mu * mu;
        float rstd = rsqrtf(var + 1e-5f);

        float o0 = 0.f, o1 = 0.f;
        #pragma unroll
        for (int i = 0; i < 4; ++i) {
            float r = (z[i] - mu) * rstd * gv[i] + bv[i];
            r = fmaxf(r, 0.f);
            o0 += r * w2a[i];
            o1 += r * w2b[i];
        }
        #pragma unroll
        for (int off = 32; off; off >>= 1) {
            o0 += __shfl_xor(o0, off);
            o1 += __shfl_xor(o1, off);
        }
        if (lane == 0) {
            *(float2*)(out + 2 * e) = make_float2(o0 + b20, o1 + b21);
        }
    }
}

extern "C" void kernel_launch(void* const* d_in, const int* in_sizes, int n_in,
                              void* d_out, int out_size, void* d_ws, size_t ws_size,
                              hipStream_t stream) {
    const float* h     = (const float*)d_in[0];
    const float* cls   = (const float*)d_in[1];
    const float* polar = (const float*)d_in[2];
    const int*   src   = (const int*)d_in[3];
    const int*   dst   = (const int*)d_in[4];
    const float* W1    = (const float*)d_in[5];
    const float* b1    = (const float*)d_in[6];
    const float* gamma = (const float*)d_in[7];
    const float* beta  = (const float*)d_in[8];
    const float* W2    = (const float*)d_in[9];
    const float* b2    = (const float*)d_in[10];
    float* out = (float*)d_out;

    char* ws = (char*)d_ws;
    _Float16*       P   = (_Float16*)ws;                      // N*512*2  = 102,400,000 B
    unsigned short* F   = (unsigned short*)(ws + 102400000);  // N*128*2  =  25,600,000 B
    unsigned short* W1T = (unsigned short*)(ws + 128000000);  // 512*128*2 =    131,072 B

    // Kernel 1: 12,865,536 work items exactly = 50256 * 256
    build_tables<<<50256, 256, 0, stream>>>(h, cls, W1, F, W1T);

    // Kernel 2: M=100000 in 64-row tiles (1563), N=512 in 128-col tiles (4)
    dim3 g2(1563, 4);
    p_gemm<<<g2, 256, 0, stream>>>(F, W1T, P);

    // Kernel 3: one wave per edge, grid-stride
    edge_kernel<<<K3_BLOCKS, 256, 0, stream>>>(P, src, dst, polar, W1, b1, gamma, beta, W2, b2, out);
}

// Round 2
// 325.265 us; speedup vs baseline: 1.4497x; 1.4497x over previous
//
#include <hip/hip_runtime.h>
#include <hip/hip_bf16.h>

#define NN 100000
#define EE 1000000
#define H_DIM 124
#define PCOLS 512
#define LDK 136   // 128 + 8 bf16 pad: dword stride 68 -> conflict-free b128, 16B aligned

typedef float f32x4 __attribute__((ext_vector_type(4)));
typedef short bf16x8 __attribute__((ext_vector_type(8)));
typedef _Float16 h2 __attribute__((ext_vector_type(2)));

__device__ __forceinline__ unsigned short f2bf(float f) {
    unsigned int x = __float_as_uint(f);
    unsigned int r = (x + 0x7FFFu + ((x >> 16) & 1u)) >> 16;
    return (unsigned short)r;
}

__device__ __forceinline__ float fdot2(h2 a, h2 b, float c) {
#if __has_builtin(__builtin_amdgcn_fdot2)
    return __builtin_amdgcn_fdot2(a, b, c, false);
#else
    return c + (float)a[0] * (float)b[0] + (float)a[1] * (float)b[1];
#endif
}

struct alignas(16) H8 { h2 p[4]; };

// ---------------- Kernel 1: build F (bf16 [N,128]) and W1T (bf16 [512,128]) ----------------
__global__ __launch_bounds__(256) void build_tables(const float* __restrict__ h,
                                                    const float* __restrict__ cls,
                                                    const float* __restrict__ W1,
                                                    unsigned short* __restrict__ F,
                                                    unsigned short* __restrict__ W1T) {
    int tid = blockIdx.x * 256 + threadIdx.x;
    if (tid < NN * 128) {
        int n = tid >> 7, j = tid & 127;
        float v;
        if (j < H_DIM) {
            v = h[n * H_DIM + j];
        } else {
            const float* c = cls + n * 4;
            float c0 = c[0], c1 = c[1], c2 = c[2], c3 = c[3];
            float m = fmaxf(fmaxf(c0, c1), fmaxf(c2, c3));
            float e0 = __expf(c0 - m), e1 = __expf(c1 - m), e2 = __expf(c2 - m), e3 = __expf(c3 - m);
            float s = e0 + e1 + e2 + e3;
            int jj = j - H_DIM;
            float ev = (jj == 0) ? e0 : (jj == 1) ? e1 : (jj == 2) ? e2 : e3;
            v = ev / s;
        }
        F[tid] = f2bf(v);
    } else if (tid < NN * 128 + PCOLS * 128) {
        int t2 = tid - NN * 128;
        int j = t2 >> 7, k = t2 & 127;           // j: output col of W1cat (0..511), k: input row (0..127)
        int row = (j < 256) ? k : (130 + k);
        int col = (j < 256) ? j : (j - 256);
        W1T[t2] = f2bf(W1[row * 256 + col]);
    }
}

// ---------------- Kernel 2: P = F @ W1cat, [N,128]x[128,512] -> fp16 P [N,512] ----------------
// A-tile (64 rows of F) staged once, looped over all 4 column chunks of B.
__global__ __launch_bounds__(256) void p_gemm(const unsigned short* __restrict__ F,
                                              const unsigned short* __restrict__ W1T,
                                              _Float16* __restrict__ P) {
    __shared__ unsigned short As[64 * LDK];
    __shared__ unsigned short Bs[128 * LDK];
    const int m0 = blockIdx.x * 64;
    const int t = threadIdx.x;

    // Stage A tile: 64 rows x 128 bf16 (16B chunks)
    #pragma unroll
    for (int it = 0; it < 4; ++it) {
        int chunk = t + it * 256;
        int r = chunk >> 4, c = chunk & 15;
        float4 v = make_float4(0.f, 0.f, 0.f, 0.f);
        int row = m0 + r;
        if (row < NN) v = *(const float4*)(F + row * 128 + c * 8);
        *(float4*)(&As[r * LDK + c * 8]) = v;
    }

    const int wave = t >> 6, lane = t & 63;
    const int wm = wave & 1, wn = wave >> 1;     // 2x2 wave grid: 32 rows x 64 cols per wave
    const int lm = lane & 15, quad = lane >> 4;

    for (int cchunk = 0; cchunk < 4; ++cchunk) {
        const int n0 = cchunk * 128;
        if (cchunk) __syncthreads();             // finish reading Bs before overwrite
        // Stage B chunk: 128 rows x 128 bf16
        #pragma unroll
        for (int it = 0; it < 8; ++it) {
            int chunk = t + it * 256;
            int r = chunk >> 4, c = chunk & 15;
            float4 v = *(const float4*)(W1T + (n0 + r) * 128 + c * 8);
            *(float4*)(&Bs[r * LDK + c * 8]) = v;
        }
        __syncthreads();

        f32x4 acc[2][4];
        #pragma unroll
        for (int mt = 0; mt < 2; ++mt)
            #pragma unroll
            for (int nt = 0; nt < 4; ++nt)
                acc[mt][nt] = (f32x4){0.f, 0.f, 0.f, 0.f};

        #pragma unroll
        for (int s = 0; s < 4; ++s) {
            int k0 = s * 32 + quad * 8;
            bf16x8 a[2], b[4];
            #pragma unroll
            for (int mt = 0; mt < 2; ++mt)
                a[mt] = *(const bf16x8*)(&As[(wm * 32 + mt * 16 + lm) * LDK + k0]);
            #pragma unroll
            for (int nt = 0; nt < 4; ++nt)
                b[nt] = *(const bf16x8*)(&Bs[(wn * 64 + nt * 16 + lm) * LDK + k0]);
            #pragma unroll
            for (int mt = 0; mt < 2; ++mt)
                #pragma unroll
                for (int nt = 0; nt < 4; ++nt)
                    acc[mt][nt] = __builtin_amdgcn_mfma_f32_16x16x32_bf16(a[mt], b[nt], acc[mt][nt], 0, 0, 0);
        }

        // C/D layout (16x16x32): col = lane&15, row = quad*4 + reg
        #pragma unroll
        for (int mt = 0; mt < 2; ++mt) {
            #pragma unroll
            for (int nt = 0; nt < 4; ++nt) {
                int col = n0 + wn * 64 + nt * 16 + lm;
                #pragma unroll
                for (int r = 0; r < 4; ++r) {
                    int row = m0 + wm * 32 + mt * 16 + quad * 4 + r;
                    if (row < NN) P[(size_t)row * PCOLS + col] = (_Float16)acc[mt][nt][r];
                }
            }
        }
    }
}

// ---------------- Kernel 3: per-edge gather + LN + ReLU + W2 ----------------
// 32 lanes per edge, 2 edges per wave, 8 elems (4 fp16x2 packs) per lane.
#define K3_BLOCKS 2048
#define K3_WAVES (K3_BLOCKS * 4)

__global__ __launch_bounds__(256) void edge_kernel(const _Float16* __restrict__ P,
                                                   const int* __restrict__ src,
                                                   const int* __restrict__ dst,
                                                   const float* __restrict__ polar,
                                                   const float* __restrict__ W1,
                                                   const float* __restrict__ b1,
                                                   const float* __restrict__ gamma,
                                                   const float* __restrict__ beta,
                                                   const float* __restrict__ W2,
                                                   const float* __restrict__ b2,
                                                   float* __restrict__ out) {
    const int lane = threadIdx.x & 63;
    const int il   = lane & 31;                  // lane within edge-group
    const int half = lane >> 5;                  // which edge of the pair
    const int wid  = blockIdx.x * 4 + (threadIdx.x >> 6);
    const int jb   = il * 8;                     // first element index of this lane

    // Packed fp16 constants: 7 arrays x 4 half2
    h2 w0c[4], w1c[4], b1c[4], gc[4], bc[4], w2ac[4], w2bc[4];
    #pragma unroll
    for (int p = 0; p < 4; ++p) {
        int j = jb + 2 * p;
        float2 a0 = *(const float2*)(W1 + 128 * 256 + j);
        float2 a1 = *(const float2*)(W1 + 129 * 256 + j);
        float2 ab = *(const float2*)(b1 + j);
        float2 ag = *(const float2*)(gamma + j);
        float2 ae = *(const float2*)(beta + j);
        float4 w2v = *(const float4*)(W2 + 2 * j); // (a_j, b_j, a_j+1, b_j+1)
        w0c[p]  = (h2){(_Float16)a0.x, (_Float16)a0.y};
        w1c[p]  = (h2){(_Float16)a1.x, (_Float16)a1.y};
        b1c[p]  = (h2){(_Float16)ab.x, (_Float16)ab.y};
        gc[p]   = (h2){(_Float16)ag.x, (_Float16)ag.y};
        bc[p]   = (h2){(_Float16)ae.x, (_Float16)ae.y};
        w2ac[p] = (h2){(_Float16)w2v.x, (_Float16)w2v.z};
        w2bc[p] = (h2){(_Float16)w2v.y, (_Float16)w2v.w};
    }
    const float b20 = b2[0], b21 = b2[1];
    const h2 onep = (h2){(_Float16)1.0f, (_Float16)1.0f};
    const h2 zerop = (h2){(_Float16)0.0f, (_Float16)0.0f};

    const int stride = K3_WAVES * 2;
    const int base = wid * 2;

    // --- software pipeline: 2-deep indices, 1-deep P rows ---
    int s0, d0, s1, d1;
    float q00, q01, q10, q11;
    {
        int b = base, e = (b < EE) ? (b + half) : 0;
        s0 = src[e]; d0 = dst[e];
        float2 pw = *(const float2*)(polar + 2 * e);
        q00 = pw.x; q01 = pw.y;
    }
    {
        int b = base + stride, e = (b < EE) ? (b + half) : 0;
        s1 = src[e]; d1 = dst[e];
        float2 pw = *(const float2*)(polar + 2 * e);
        q10 = pw.x; q11 = pw.y;
    }
    H8 ps = *(const H8*)(P + (size_t)s0 * PCOLS + jb);
    H8 pd = *(const H8*)(P + (size_t)d0 * PCOLS + 256 + jb);

    for (int e = base; e < EE; e += stride) {
        // prefetch indices for e + 2*stride
        int s2, d2; float q20, q21;
        {
            int b = e + 2 * stride, ec = (b < EE) ? (b + half) : 0;
            s2 = src[ec]; d2 = dst[ec];
            float2 pw = *(const float2*)(polar + 2 * ec);
            q20 = pw.x; q21 = pw.y;
        }
        // prefetch P rows for e + stride
        H8 psn = *(const H8*)(P + (size_t)s1 * PCOLS + jb);
        H8 pdn = *(const H8*)(P + (size_t)d1 * PCOLS + 256 + jb);

        // ---- compute edge e + half ----
        h2 p0h = (h2){(_Float16)q00, (_Float16)q00};
        h2 p1h = (h2){(_Float16)q01, (_Float16)q01};
        h2 z[4];
        float sum = 0.f, ss = 0.f;
        #pragma unroll
        for (int p = 0; p < 4; ++p) {
            h2 c = w0c[p] * p0h + (w1c[p] * p1h + b1c[p]);
            z[p] = (ps.p[p] + pd.p[p]) + c;
            sum = fdot2(z[p], onep, sum);
            ss  = fdot2(z[p], z[p], ss);
        }
        #pragma unroll
        for (int off = 16; off; off >>= 1) {
            sum += __shfl_xor(sum, off);
            ss  += __shfl_xor(ss, off);
        }
        float mu   = sum * (1.0f / 256.0f);
        float var  = ss * (1.0f / 256.0f) - mu * mu;
        float rstd = rsqrtf(var + 1e-5f);
        h2 muh = (h2){(_Float16)mu, (_Float16)mu};
        h2 rsh = (h2){(_Float16)rstd, (_Float16)rstd};

        float o0 = 0.f, o1 = 0.f;
        #pragma unroll
        for (int p = 0; p < 4; ++p) {
            h2 t = (z[p] - muh) * rsh;
            h2 u = t * gc[p] + bc[p];
            u = __builtin_elementwise_max(u, zerop);
            o0 = fdot2(u, w2ac[p], o0);
            o1 = fdot2(u, w2bc[p], o1);
        }
        #pragma unroll
        for (int off = 16; off; off >>= 1) {
            o0 += __shfl_xor(o0, off);
            o1 += __shfl_xor(o1, off);
        }
        if (il == 0) {
            *(float2*)(out + 2 * (e + half)) = make_float2(o0 + b20, o1 + b21);
        }

        // rotate pipeline
        s0 = s1; d0 = d1; q00 = q10; q01 = q11;
        s1 = s2; d1 = d2; q10 = q20; q11 = q21;
        ps = psn; pd = pdn;
    }
}

extern "C" void kernel_launch(void* const* d_in, const int* in_sizes, int n_in,
                              void* d_out, int out_size, void* d_ws, size_t ws_size,
                              hipStream_t stream) {
    const float* h     = (const float*)d_in[0];
    const float* cls   = (const float*)d_in[1];
    const float* polar = (const float*)d_in[2];
    const int*   src   = (const int*)d_in[3];
    const int*   dst   = (const int*)d_in[4];
    const float* W1    = (const float*)d_in[5];
    const float* b1    = (const float*)d_in[6];
    const float* gamma = (const float*)d_in[7];
    const float* beta  = (const float*)d_in[8];
    const float* W2    = (const float*)d_in[9];
    const float* b2    = (const float*)d_in[10];
    float* out = (float*)d_out;

    char* ws = (char*)d_ws;
    _Float16*       P   = (_Float16*)ws;                      // N*512*2  = 102,400,000 B
    unsigned short* F   = (unsigned short*)(ws + 102400000);  // N*128*2  =  25,600,000 B
    unsigned short* W1T = (unsigned short*)(ws + 128000000);  // 512*128*2 =    131,072 B

    // Kernel 1: 12,865,536 work items exactly = 50256 * 256
    build_tables<<<50256, 256, 0, stream>>>(h, cls, W1, F, W1T);

    // Kernel 2: M=100000 in 64-row tiles; each block covers all 512 cols
    p_gemm<<<1563, 256, 0, stream>>>(F, W1T, P);

    // Kernel 3: 2 edges per wave, grid-stride
    edge_kernel<<<K3_BLOCKS, 256, 0, stream>>>(P, src, dst, polar, W1, b1, gamma, beta, W2, b2, out);
}

// Round 3
// 303.105 us; speedup vs baseline: 1.5557x; 1.0731x over previous
//
#include <hip/hip_runtime.h>
#include <hip/hip_bf16.h>

#define NN 100000
#define EE 1000000
#define H_DIM 124
#define PCOLS 512
#define LDK 136   // 128 + 8 bf16 pad: dword stride 68 -> conflict-free b128, 16B aligned
#define CW 132    // f32 staging stride in dwords: rows 4 apart -> +16 banks -> 2-way (free)

typedef float f32x4 __attribute__((ext_vector_type(4)));
typedef short bf16x8 __attribute__((ext_vector_type(8)));
typedef _Float16 h2 __attribute__((ext_vector_type(2)));

__device__ __forceinline__ unsigned short f2bf(float f) {
    unsigned int x = __float_as_uint(f);
    unsigned int r = (x + 0x7FFFu + ((x >> 16) & 1u)) >> 16;
    return (unsigned short)r;
}
__device__ __forceinline__ unsigned int pk2bf(float a, float b) {
    return (unsigned int)f2bf(a) | ((unsigned int)f2bf(b) << 16);
}
__device__ __forceinline__ unsigned int pk2h(float a, float b) {
    h2 v = (h2){(_Float16)a, (_Float16)b};
    return __builtin_bit_cast(unsigned int, v);
}

__device__ __forceinline__ float fdot2(h2 a, h2 b, float c) {
#if __has_builtin(__builtin_amdgcn_fdot2)
    return __builtin_amdgcn_fdot2(a, b, c, false);
#else
    return c + (float)a[0] * (float)b[0] + (float)a[1] * (float)b[1];
#endif
}

struct alignas(16) H8 { h2 p[4]; };

// ---------------- Kernel 1: W1T (bf16 [512,128]) only ----------------
__global__ __launch_bounds__(256) void build_w1t(const float* __restrict__ W1,
                                                 unsigned short* __restrict__ W1T) {
    int t2 = blockIdx.x * 256 + threadIdx.x;     // 0 .. 65535
    int j = t2 >> 7, k = t2 & 127;               // j: output col of W1cat (0..511), k: input row
    int row = (j < 256) ? k : (130 + k);
    int col = (j < 256) ? j : (j - 256);
    W1T[t2] = f2bf(W1[row * 256 + col]);
}

// ---------------- Kernel 2: fused F-build + P = F @ W1cat -> fp16 P [N,512] ----------------
__global__ __launch_bounds__(256) void p_gemm(const float* __restrict__ h,
                                              const float* __restrict__ cls,
                                              const unsigned short* __restrict__ W1T,
                                              _Float16* __restrict__ P) {
    __shared__ alignas(16) unsigned short As[64 * LDK];    // 17408 B
    __shared__ alignas(16) unsigned short Bs[128 * LDK];   // 34816 B (aliased as f32 staging)
    float* Cs = (float*)&Bs[0];                            // [64][CW] f32 = 33792 B
    const int m0 = blockIdx.x * 64;
    const int t = threadIdx.x;

    // ---- Stage A tile: build F rows on the fly (h copy + cls softmax), bf16 ----
    #pragma unroll
    for (int it = 0; it < 4; ++it) {
        int chunk = t + it * 256;                // 0..1023
        int r = chunk >> 4, c8 = chunk & 15;     // row in tile, col-chunk of 8
        int row = m0 + r;
        unsigned int w0 = 0, w1 = 0, w2 = 0, w3 = 0;
        if (row < NN) {
            if (c8 < 15) {
                const float* hp = h + (size_t)row * H_DIM + c8 * 8;
                float4 v0 = *(const float4*)(hp);
                float4 v1 = *(const float4*)(hp + 4);
                w0 = pk2bf(v0.x, v0.y); w1 = pk2bf(v0.z, v0.w);
                w2 = pk2bf(v1.x, v1.y); w3 = pk2bf(v1.z, v1.w);
            } else {
                float4 v0 = *(const float4*)(h + (size_t)row * H_DIM + 120);
                float4 c = *(const float4*)(cls + (size_t)row * 4);
                float m = fmaxf(fmaxf(c.x, c.y), fmaxf(c.z, c.w));
                float e0 = __expf(c.x - m), e1 = __expf(c.y - m);
                float e2 = __expf(c.z - m), e3 = __expf(c.w - m);
                float inv = 1.0f / (e0 + e1 + e2 + e3);
                w0 = pk2bf(v0.x, v0.y); w1 = pk2bf(v0.z, v0.w);
                w2 = pk2bf(e0 * inv, e1 * inv); w3 = pk2bf(e2 * inv, e3 * inv);
            }
        }
        *(uint4*)(&As[r * LDK + c8 * 8]) = make_uint4(w0, w1, w2, w3);
    }
    __syncthreads();

    const int wave = t >> 6, lane = t & 63;
    const int wm = wave & 1, wn = wave >> 1;     // 2x2 wave grid: 32 rows x 64 cols per wave
    const int lm = lane & 15, quad = lane >> 4;

    // ---- Hoist A fragments (chunk-invariant): 8 x bf16x8 = 32 VGPRs ----
    bf16x8 afrag[4][2];
    #pragma unroll
    for (int s = 0; s < 4; ++s) {
        int k0 = s * 32 + quad * 8;
        #pragma unroll
        for (int mt = 0; mt < 2; ++mt)
            afrag[s][mt] = *(const bf16x8*)(&As[(wm * 32 + mt * 16 + lm) * LDK + k0]);
    }

    for (int cchunk = 0; cchunk < 4; ++cchunk) {
        const int n0 = cchunk * 128;
        if (cchunk) __syncthreads();             // epilogue reads of Cs(=Bs) done before restage
        // ---- Stage B chunk: 128 rows x 128 bf16 ----
        #pragma unroll
        for (int it = 0; it < 8; ++it) {
            int chunk = t + it * 256;
            int r = chunk >> 4, c = chunk & 15;
            float4 v = *(const float4*)(W1T + (n0 + r) * 128 + c * 8);
            *(float4*)(&Bs[r * LDK + c * 8]) = v;
        }
        __syncthreads();

        f32x4 acc[2][4];
        #pragma unroll
        for (int mt = 0; mt < 2; ++mt)
            #pragma unroll
            for (int nt = 0; nt < 4; ++nt)
                acc[mt][nt] = (f32x4){0.f, 0.f, 0.f, 0.f};

        #pragma unroll
        for (int s = 0; s < 4; ++s) {
            int k0 = s * 32 + quad * 8;
            bf16x8 b[4];
            #pragma unroll
            for (int nt = 0; nt < 4; ++nt)
                b[nt] = *(const bf16x8*)(&Bs[(wn * 64 + nt * 16 + lm) * LDK + k0]);
            #pragma unroll
            for (int mt = 0; mt < 2; ++mt)
                #pragma unroll
                for (int nt = 0; nt < 4; ++nt)
                    acc[mt][nt] = __builtin_amdgcn_mfma_f32_16x16x32_bf16(afrag[s][mt], b[nt], acc[mt][nt], 0, 0, 0);
        }
        __syncthreads();                          // all Bs reads done before staging overwrite

        // ---- Epilogue: acc -> LDS f32 staging -> coalesced fp16 dwordx4 stores ----
        // C/D layout (16x16x32): col = lane&15, row = quad*4 + reg
        #pragma unroll
        for (int mt = 0; mt < 2; ++mt)
            #pragma unroll
            for (int nt = 0; nt < 4; ++nt) {
                int col = wn * 64 + nt * 16 + lm;
                int rb  = wm * 32 + mt * 16 + quad * 4;
                #pragma unroll
                for (int r = 0; r < 4; ++r)
                    Cs[(rb + r) * CW + col] = acc[mt][nt][r];
            }
        __syncthreads();

        #pragma unroll
        for (int it = 0; it < 4; ++it) {
            int chunk = t + it * 256;
            int r = chunk >> 4, c8 = chunk & 15;
            float4 a = *(const float4*)(Cs + r * CW + c8 * 8);
            float4 b = *(const float4*)(Cs + r * CW + c8 * 8 + 4);
            uint4 o = make_uint4(pk2h(a.x, a.y), pk2h(a.z, a.w),
                                 pk2h(b.x, b.y), pk2h(b.z, b.w));
            int row = m0 + r;
            if (row < NN)
                *(uint4*)(P + (size_t)row * PCOLS + n0 + c8 * 8) = o;
        }
    }
}

// ---------------- Kernel 3: per-edge gather + LN + ReLU + W2 ----------------
// 32 lanes per edge, 2 edges per wave, 8 elems (4 fp16x2 packs) per lane.
#define K3_BLOCKS 2048
#define K3_WAVES (K3_BLOCKS * 4)

__global__ __launch_bounds__(256) void edge_kernel(const _Float16* __restrict__ P,
                                                   const int* __restrict__ src,
                                                   const int* __restrict__ dst,
                                                   const float* __restrict__ polar,
                                                   const float* __restrict__ W1,
                                                   const float* __restrict__ b1,
                                                   const float* __restrict__ gamma,
                                                   const float* __restrict__ beta,
                                                   const float* __restrict__ W2,
                                                   const float* __restrict__ b2,
                                                   float* __restrict__ out) {
    const int lane = threadIdx.x & 63;
    const int il   = lane & 31;                  // lane within edge-group
    const int half = lane >> 5;                  // which edge of the pair
    const int wid  = blockIdx.x * 4 + (threadIdx.x >> 6);
    const int jb   = il * 8;                     // first element index of this lane

    // Packed fp16 constants: 7 arrays x 4 half2
    h2 w0c[4], w1c[4], b1c[4], gc[4], bc[4], w2ac[4], w2bc[4];
    #pragma unroll
    for (int p = 0; p < 4; ++p) {
        int j = jb + 2 * p;
        float2 a0 = *(const float2*)(W1 + 128 * 256 + j);
        float2 a1 = *(const float2*)(W1 + 129 * 256 + j);
        float2 ab = *(const float2*)(b1 + j);
        float2 ag = *(const float2*)(gamma + j);
        float2 ae = *(const float2*)(beta + j);
        float4 w2v = *(const float4*)(W2 + 2 * j); // (a_j, b_j, a_j+1, b_j+1)
        w0c[p]  = (h2){(_Float16)a0.x, (_Float16)a0.y};
        w1c[p]  = (h2){(_Float16)a1.x, (_Float16)a1.y};
        b1c[p]  = (h2){(_Float16)ab.x, (_Float16)ab.y};
        gc[p]   = (h2){(_Float16)ag.x, (_Float16)ag.y};
        bc[p]   = (h2){(_Float16)ae.x, (_Float16)ae.y};
        w2ac[p] = (h2){(_Float16)w2v.x, (_Float16)w2v.z};
        w2bc[p] = (h2){(_Float16)w2v.y, (_Float16)w2v.w};
    }
    const float b20 = b2[0], b21 = b2[1];
    const h2 onep = (h2){(_Float16)1.0f, (_Float16)1.0f};
    const h2 zerop = (h2){(_Float16)0.0f, (_Float16)0.0f};

    const int stride = K3_WAVES * 2;
    const int base = wid * 2;

    // --- software pipeline: 2-deep indices, 1-deep P rows ---
    int s0, d0, s1, d1;
    float q00, q01, q10, q11;
    {
        int b = base, e = (b < EE) ? (b + half) : 0;
        s0 = src[e]; d0 = dst[e];
        float2 pw = *(const float2*)(polar + 2 * e);
        q00 = pw.x; q01 = pw.y;
    }
    {
        int b = base + stride, e = (b < EE) ? (b + half) : 0;
        s1 = src[e]; d1 = dst[e];
        float2 pw = *(const float2*)(polar + 2 * e);
        q10 = pw.x; q11 = pw.y;
    }
    H8 ps = *(const H8*)(P + (size_t)s0 * PCOLS + jb);
    H8 pd = *(const H8*)(P + (size_t)d0 * PCOLS + 256 + jb);

    for (int e = base; e < EE; e += stride) {
        // prefetch indices for e + 2*stride
        int s2, d2; float q20, q21;
        {
            int b = e + 2 * stride, ec = (b < EE) ? (b + half) : 0;
            s2 = src[ec]; d2 = dst[ec];
            float2 pw = *(const float2*)(polar + 2 * ec);
            q20 = pw.x; q21 = pw.y;
        }
        // prefetch P rows for e + stride
        H8 psn = *(const H8*)(P + (size_t)s1 * PCOLS + jb);
        H8 pdn = *(const H8*)(P + (size_t)d1 * PCOLS + 256 + jb);

        // ---- compute edge e + half ----
        h2 p0h = (h2){(_Float16)q00, (_Float16)q00};
        h2 p1h = (h2){(_Float16)q01, (_Float16)q01};
        h2 z[4];
        float sum = 0.f, ss = 0.f;
        #pragma unroll
        for (int p = 0; p < 4; ++p) {
            h2 c = w0c[p] * p0h + (w1c[p] * p1h + b1c[p]);
            z[p] = (ps.p[p] + pd.p[p]) + c;
            sum = fdot2(z[p], onep, sum);
            ss  = fdot2(z[p], z[p], ss);
        }
        #pragma unroll
        for (int off = 16; off; off >>= 1) {
            sum += __shfl_xor(sum, off);
            ss  += __shfl_xor(ss, off);
        }
        float mu   = sum * (1.0f / 256.0f);
        float var  = ss * (1.0f / 256.0f) - mu * mu;
        float rstd = rsqrtf(var + 1e-5f);
        h2 muh = (h2){(_Float16)mu, (_Float16)mu};
        h2 rsh = (h2){(_Float16)rstd, (_Float16)rstd};

        float o0 = 0.f, o1 = 0.f;
        #pragma unroll
        for (int p = 0; p < 4; ++p) {
            h2 t = (z[p] - muh) * rsh;
            h2 u = t * gc[p] + bc[p];
            u = __builtin_elementwise_max(u, zerop);
            o0 = fdot2(u, w2ac[p], o0);
            o1 = fdot2(u, w2bc[p], o1);
        }
        #pragma unroll
        for (int off = 16; off; off >>= 1) {
            o0 += __shfl_xor(o0, off);
            o1 += __shfl_xor(o1, off);
        }
        if (il == 0) {
            *(float2*)(out + 2 * (e + half)) = make_float2(o0 + b20, o1 + b21);
        }

        // rotate pipeline
        s0 = s1; d0 = d1; q00 = q10; q01 = q11;
        s1 = s2; d1 = d2; q10 = q20; q11 = q21;
        ps = psn; pd = pdn;
    }
}

extern "C" void kernel_launch(void* const* d_in, const int* in_sizes, int n_in,
                              void* d_out, int out_size, void* d_ws, size_t ws_size,
                              hipStream_t stream) {
    const float* h     = (const float*)d_in[0];
    const float* cls   = (const float*)d_in[1];
    const float* polar = (const float*)d_in[2];
    const int*   src   = (const int*)d_in[3];
    const int*   dst   = (const int*)d_in[4];
    const float* W1    = (const float*)d_in[5];
    const float* b1    = (const float*)d_in[6];
    const float* gamma = (const float*)d_in[7];
    const float* beta  = (const float*)d_in[8];
    const float* W2    = (const float*)d_in[9];
    const float* b2    = (const float*)d_in[10];
    float* out = (float*)d_out;

    char* ws = (char*)d_ws;
    _Float16*       P   = (_Float16*)ws;                      // N*512*2  = 102,400,000 B
    unsigned short* W1T = (unsigned short*)(ws + 102400000);  // 512*128*2 = 131,072 B

    // Kernel 1: W1T transpose+cast, 65536 elems = 256 blocks x 256 threads
    build_w1t<<<256, 256, 0, stream>>>(W1, W1T);

    // Kernel 2: fused F-build + GEMM, M=100000 in 64-row tiles
    p_gemm<<<1563, 256, 0, stream>>>(h, cls, W1T, P);

    // Kernel 3: 2 edges per wave, grid-stride
    edge_kernel<<<K3_BLOCKS, 256, 0, stream>>>(P, src, dst, polar, W1, b1, gamma, beta, W2, b2, out);
}

// Round 4
// 292.708 us; speedup vs baseline: 1.6110x; 1.0355x over previous
//
#include <hip/hip_runtime.h>
#include <hip/hip_bf16.h>

#define NN 100000
#define EE 1000000
#define H_DIM 124
#define PCOLS 512
#define LDK 136   // 128 + 8 bf16 pad
#define CW 132    // f32 staging stride in dwords

typedef float f32x4 __attribute__((ext_vector_type(4)));
typedef short bf16x8 __attribute__((ext_vector_type(8)));
typedef _Float16 h2 __attribute__((ext_vector_type(2)));

__device__ __forceinline__ unsigned short f2bf(float f) {
    unsigned int x = __float_as_uint(f);
    unsigned int r = (x + 0x7FFFu + ((x >> 16) & 1u)) >> 16;
    return (unsigned short)r;
}
__device__ __forceinline__ unsigned int pk2bf(float a, float b) {
    return (unsigned int)f2bf(a) | ((unsigned int)f2bf(b) << 16);
}
__device__ __forceinline__ unsigned int pk2h(float a, float b) {
    h2 v = (h2){(_Float16)a, (_Float16)b};
    return __builtin_bit_cast(unsigned int, v);
}

__device__ __forceinline__ float fdot2(h2 a, h2 b, float c) {
#if __has_builtin(__builtin_amdgcn_fdot2)
    return __builtin_amdgcn_fdot2(a, b, c, false);
#else
    return c + (float)a[0] * (float)b[0] + (float)a[1] * (float)b[1];
#endif
}

#if __has_builtin(__builtin_amdgcn_update_dpp)
template <int CTRL>
__device__ __forceinline__ float dpp_add(float x) {
    int xi = __builtin_bit_cast(int, x);
    int t = __builtin_amdgcn_update_dpp(xi, xi, CTRL, 0xF, 0xF, false);
    return x + __builtin_bit_cast(float, t);
}
__device__ __forceinline__ float reduce16(float x) {
    x = dpp_add<0x128>(x);   // row_ror:8
    x = dpp_add<0x124>(x);   // row_ror:4
    x = dpp_add<0x122>(x);   // row_ror:2
    x = dpp_add<0x121>(x);   // row_ror:1
    return x;
}
#else
__device__ __forceinline__ float reduce16(float x) {
    x += __shfl_xor(x, 8); x += __shfl_xor(x, 4);
    x += __shfl_xor(x, 2); x += __shfl_xor(x, 1);
    return x;
}
#endif

struct alignas(16) H8 { h2 p[4]; };

// ---------------- Kernel 1: W1T (bf16 [512,128]) ----------------
__global__ __launch_bounds__(256) void build_w1t(const float* __restrict__ W1,
                                                 unsigned short* __restrict__ W1T) {
    int t2 = blockIdx.x * 256 + threadIdx.x;     // 0 .. 65535
    int j = t2 >> 7, k = t2 & 127;
    int row = (j < 256) ? k : (130 + k);
    int col = (j < 256) ? j : (j - 256);
    W1T[t2] = f2bf(W1[row * 256 + col]);
}

// ---------------- Kernel 2: fused F-build + P = F @ W1cat (+b1 on dst half) -> fp16 ----------------
__global__ __launch_bounds__(256) void p_gemm(const float* __restrict__ h,
                                              const float* __restrict__ cls,
                                              const unsigned short* __restrict__ W1T,
                                              const float* __restrict__ b1,
                                              _Float16* __restrict__ P) {
    __shared__ alignas(16) unsigned short As[64 * LDK];
    __shared__ alignas(16) unsigned short Bs[128 * LDK];
    float* Cs = (float*)&Bs[0];
    const int m0 = blockIdx.x * 64;
    const int t = threadIdx.x;

    #pragma unroll
    for (int it = 0; it < 4; ++it) {
        int chunk = t + it * 256;
        int r = chunk >> 4, c8 = chunk & 15;
        int row = m0 + r;
        unsigned int w0 = 0, w1 = 0, w2 = 0, w3 = 0;
        if (row < NN) {
            if (c8 < 15) {
                const float* hp = h + (size_t)row * H_DIM + c8 * 8;
                float4 v0 = *(const float4*)(hp);
                float4 v1 = *(const float4*)(hp + 4);
                w0 = pk2bf(v0.x, v0.y); w1 = pk2bf(v0.z, v0.w);
                w2 = pk2bf(v1.x, v1.y); w3 = pk2bf(v1.z, v1.w);
            } else {
                float4 v0 = *(const float4*)(h + (size_t)row * H_DIM + 120);
                float4 c = *(const float4*)(cls + (size_t)row * 4);
                float m = fmaxf(fmaxf(c.x, c.y), fmaxf(c.z, c.w));
                float e0 = __expf(c.x - m), e1 = __expf(c.y - m);
                float e2 = __expf(c.z - m), e3 = __expf(c.w - m);
                float inv = 1.0f / (e0 + e1 + e2 + e3);
                w0 = pk2bf(v0.x, v0.y); w1 = pk2bf(v0.z, v0.w);
                w2 = pk2bf(e0 * inv, e1 * inv); w3 = pk2bf(e2 * inv, e3 * inv);
            }
        }
        *(uint4*)(&As[r * LDK + c8 * 8]) = make_uint4(w0, w1, w2, w3);
    }
    __syncthreads();

    const int wave = t >> 6, lane = t & 63;
    const int wm = wave & 1, wn = wave >> 1;
    const int lm = lane & 15, quad = lane >> 4;

    bf16x8 afrag[4][2];
    #pragma unroll
    for (int s = 0; s < 4; ++s) {
        int k0 = s * 32 + quad * 8;
        #pragma unroll
        for (int mt = 0; mt < 2; ++mt)
            afrag[s][mt] = *(const bf16x8*)(&As[(wm * 32 + mt * 16 + lm) * LDK + k0]);
    }

    for (int cchunk = 0; cchunk < 4; ++cchunk) {
        const int n0 = cchunk * 128;
        if (cchunk) __syncthreads();
        #pragma unroll
        for (int it = 0; it < 8; ++it) {
            int chunk = t + it * 256;
            int r = chunk >> 4, c = chunk & 15;
            float4 v = *(const float4*)(W1T + (n0 + r) * 128 + c * 8);
            *(float4*)(&Bs[r * LDK + c * 8]) = v;
        }
        __syncthreads();

        f32x4 acc[2][4];
        #pragma unroll
        for (int mt = 0; mt < 2; ++mt)
            #pragma unroll
            for (int nt = 0; nt < 4; ++nt)
                acc[mt][nt] = (f32x4){0.f, 0.f, 0.f, 0.f};

        #pragma unroll
        for (int s = 0; s < 4; ++s) {
            int k0 = s * 32 + quad * 8;
            bf16x8 b[4];
            #pragma unroll
            for (int nt = 0; nt < 4; ++nt)
                b[nt] = *(const bf16x8*)(&Bs[(wn * 64 + nt * 16 + lm) * LDK + k0]);
            #pragma unroll
            for (int mt = 0; mt < 2; ++mt)
                #pragma unroll
                for (int nt = 0; nt < 4; ++nt)
                    acc[mt][nt] = __builtin_amdgcn_mfma_f32_16x16x32_bf16(afrag[s][mt], b[nt], acc[mt][nt], 0, 0, 0);
        }
        __syncthreads();

        #pragma unroll
        for (int mt = 0; mt < 2; ++mt)
            #pragma unroll
            for (int nt = 0; nt < 4; ++nt) {
                int col = wn * 64 + nt * 16 + lm;
                int rb  = wm * 32 + mt * 16 + quad * 4;
                #pragma unroll
                for (int r = 0; r < 4; ++r)
                    Cs[(rb + r) * CW + col] = acc[mt][nt][r];
            }
        __syncthreads();

        #pragma unroll
        for (int it = 0; it < 4; ++it) {
            int chunk = t + it * 256;
            int r = chunk >> 4, c8 = chunk & 15;
            float4 a = *(const float4*)(Cs + r * CW + c8 * 8);
            float4 b = *(const float4*)(Cs + r * CW + c8 * 8 + 4);
            if (n0 >= 256) {   // dst half: fold b1 (wave-uniform branch)
                int cb = n0 + c8 * 8 - 256;
                float4 ba = *(const float4*)(b1 + cb);
                float4 bb = *(const float4*)(b1 + cb + 4);
                a.x += ba.x; a.y += ba.y; a.z += ba.z; a.w += ba.w;
                b.x += bb.x; b.y += bb.y; b.z += bb.z; b.w += bb.w;
            }
            uint4 o = make_uint4(pk2h(a.x, a.y), pk2h(a.z, a.w),
                                 pk2h(b.x, b.y), pk2h(b.z, b.w));
            int row = m0 + r;
            if (row < NN)
                *(uint4*)(P + (size_t)row * PCOLS + n0 + c8 * 8) = o;
        }
    }
}

// ---------------- Kernel 3: edges — 16 lanes/edge, 4 edges/wave, DPP reductions ----------------
#define K3_BLOCKS 4096
#define K3_WAVES  (K3_BLOCKS * 4)      // 16384
#define K3_STRIDE (K3_WAVES * 4)       // 65536 edges per round
#define K3_ROUNDS 16                   // 16*65536 = 1,048,576 >= EE

struct EIdx { int s, d; float q0, q1; };

__device__ __forceinline__ EIdx load_idx(int eg, const int* __restrict__ src,
                                         const int* __restrict__ dst,
                                         const float* __restrict__ polar) {
    int ec = (eg < EE) ? eg : 0;
    EIdx r;
    r.s = src[ec]; r.d = dst[ec];
    float2 q = *(const float2*)(polar + 2 * ec);
    r.q0 = q.x; r.q1 = q.y;
    return r;
}

__device__ __forceinline__ void load_p(const _Float16* __restrict__ P, const EIdx& I,
                                       int il, H8* A) {
    const _Float16* ps = P + (size_t)I.s * PCOLS + il * 16;
    A[0] = *(const H8*)(ps);
    A[1] = *(const H8*)(ps + 8);
    const _Float16* pd = P + (size_t)I.d * PCOLS + 256 + il * 16;
    A[2] = *(const H8*)(pd);
    A[3] = *(const H8*)(pd + 8);
}

__global__ __launch_bounds__(256) void edge_kernel(const _Float16* __restrict__ P,
                                                   const int* __restrict__ src,
                                                   const int* __restrict__ dst,
                                                   const float* __restrict__ polar,
                                                   const float* __restrict__ W1,
                                                   const float* __restrict__ gamma,
                                                   const float* __restrict__ beta,
                                                   const float* __restrict__ W2,
                                                   const float* __restrict__ b2,
                                                   float* __restrict__ out) {
    const int lane = threadIdx.x & 63;
    const int il   = lane & 15;                  // lane within edge group
    const int g    = lane >> 4;                  // edge group 0..3
    const int wid  = blockIdx.x * 4 + (threadIdx.x >> 6);
    const int jb   = il * 16;                    // first element of this lane

    // Packed fp16 constants: 6 arrays x 8 half2 (b1 folded into P)
    h2 w0c[8], w1c[8], gc[8], bc[8], w2ac[8], w2bc[8];
    #pragma unroll
    for (int p = 0; p < 8; ++p) {
        int j = jb + 2 * p;
        float2 a0 = *(const float2*)(W1 + 128 * 256 + j);
        float2 a1 = *(const float2*)(W1 + 129 * 256 + j);
        float2 ag = *(const float2*)(gamma + j);
        float2 ae = *(const float2*)(beta + j);
        float4 w2v = *(const float4*)(W2 + 2 * j);
        w0c[p]  = (h2){(_Float16)a0.x, (_Float16)a0.y};
        w1c[p]  = (h2){(_Float16)a1.x, (_Float16)a1.y};
        gc[p]   = (h2){(_Float16)ag.x, (_Float16)ag.y};
        bc[p]   = (h2){(_Float16)ae.x, (_Float16)ae.y};
        w2ac[p] = (h2){(_Float16)w2v.x, (_Float16)w2v.z};
        w2bc[p] = (h2){(_Float16)w2v.y, (_Float16)w2v.w};
    }
    const float b20 = b2[0], b21 = b2[1];
    const h2 onep  = (h2){(_Float16)1.0f, (_Float16)1.0f};
    const h2 zerop = (h2){(_Float16)0.0f, (_Float16)0.0f};

    const int e0 = wid * 4 + g;

    EIdx I0 = load_idx(e0, src, dst, polar);
    H8 A[4]; load_p(P, I0, il, A);
    EIdx I1 = load_idx(e0 + K3_STRIDE, src, dst, polar);
    H8 B[4]; load_p(P, I1, il, B);

    #define EDGE_COMPUTE(Abuf, Ix, eg)                                        \
    {                                                                          \
        h2 p0 = (h2){(_Float16)(Ix).q0, (_Float16)(Ix).q0};                    \
        h2 p1 = (h2){(_Float16)(Ix).q1, (_Float16)(Ix).q1};                    \
        h2 z[8];                                                               \
        float sum = 0.f, ss = 0.f;                                             \
        _Pragma("unroll")                                                      \
        for (int p = 0; p < 8; ++p) {                                          \
            h2 pv = ((p < 4) ? (Abuf)[0].p[p] : (Abuf)[1].p[p - 4])            \
                  + ((p < 4) ? (Abuf)[2].p[p] : (Abuf)[3].p[p - 4]);           \
            h2 c = w0c[p] * p0 + w1c[p] * p1;                                  \
            z[p] = pv + c;                                                     \
            sum = fdot2(z[p], onep, sum);                                      \
            ss  = fdot2(z[p], z[p], ss);                                       \
        }                                                                      \
        sum = reduce16(sum); ss = reduce16(ss);                                \
        float mu   = sum * (1.0f / 256.0f);                                    \
        float var  = ss * (1.0f / 256.0f) - mu * mu;                           \
        float rstd = rsqrtf(var + 1e-5f);                                      \
        h2 muh = (h2){(_Float16)mu, (_Float16)mu};                             \
        h2 rsh = (h2){(_Float16)rstd, (_Float16)rstd};                         \
        float o0 = 0.f, o1 = 0.f;                                              \
        _Pragma("unroll")                                                      \
        for (int p = 0; p < 8; ++p) {                                          \
            h2 tt = (z[p] - muh) * rsh;                                        \
            h2 u = tt * gc[p] + bc[p];                                         \
            u = __builtin_elementwise_max(u, zerop);                           \
            o0 = fdot2(u, w2ac[p], o0);                                        \
            o1 = fdot2(u, w2bc[p], o1);                                        \
        }                                                                      \
        o0 = reduce16(o0); o1 = reduce16(o1);                                  \
        if (il == 0 && (eg) < EE)                                              \
            *(float2*)(out + 2 * (eg)) = make_float2(o0 + b20, o1 + b21);      \
    }

    #pragma unroll
    for (int r = 0; r < K3_ROUNDS; r += 2) {
        EDGE_COMPUTE(A, I0, e0 + r * K3_STRIDE);
        if (r + 2 < K3_ROUNDS) {
            I0 = load_idx(e0 + (r + 2) * K3_STRIDE, src, dst, polar);
            load_p(P, I0, il, A);
        }
        EDGE_COMPUTE(B, I1, e0 + (r + 1) * K3_STRIDE);
        if (r + 3 < K3_ROUNDS) {
            I1 = load_idx(e0 + (r + 3) * K3_STRIDE, src, dst, polar);
            load_p(P, I1, il, B);
        }
    }
    #undef EDGE_COMPUTE
}

extern "C" void kernel_launch(void* const* d_in, const int* in_sizes, int n_in,
                              void* d_out, int out_size, void* d_ws, size_t ws_size,
                              hipStream_t stream) {
    const float* h     = (const float*)d_in[0];
    const float* cls   = (const float*)d_in[1];
    const float* polar = (const float*)d_in[2];
    const int*   src   = (const int*)d_in[3];
    const int*   dst   = (const int*)d_in[4];
    const float* W1    = (const float*)d_in[5];
    const float* b1    = (const float*)d_in[6];
    const float* gamma = (const float*)d_in[7];
    const float* beta  = (const float*)d_in[8];
    const float* W2    = (const float*)d_in[9];
    const float* b2    = (const float*)d_in[10];
    float* out = (float*)d_out;

    char* ws = (char*)d_ws;
    _Float16*       P   = (_Float16*)ws;                      // N*512*2 = 102,400,000 B
    unsigned short* W1T = (unsigned short*)(ws + 102400000);  // 131,072 B

    build_w1t<<<256, 256, 0, stream>>>(W1, W1T);
    p_gemm<<<1563, 256, 0, stream>>>(h, cls, W1T, b1, P);
    edge_kernel<<<K3_BLOCKS, 256, 0, stream>>>(P, src, dst, polar, W1, gamma, beta, W2, b2, out);
}

// Round 5
// 289.709 us; speedup vs baseline: 1.6277x; 1.0104x over previous
//
#include <hip/hip_runtime.h>
#include <hip/hip_bf16.h>

#define NN 100000
#define EE 1000000
#define H_DIM 124
#define PCOLS 512
#define LDK 136   // 128 + 8 bf16 pad
#define CW 132    // f32 staging stride in dwords

typedef float f32x4 __attribute__((ext_vector_type(4)));
typedef short bf16x8 __attribute__((ext_vector_type(8)));
typedef _Float16 h2 __attribute__((ext_vector_type(2)));

__device__ __forceinline__ unsigned short f2bf(float f) {
    unsigned int x = __float_as_uint(f);
    unsigned int r = (x + 0x7FFFu + ((x >> 16) & 1u)) >> 16;
    return (unsigned short)r;
}
__device__ __forceinline__ unsigned int pk2bf(float a, float b) {
    return (unsigned int)f2bf(a) | ((unsigned int)f2bf(b) << 16);
}
__device__ __forceinline__ unsigned int pk2h(float a, float b) {
    h2 v = (h2){(_Float16)a, (_Float16)b};
    return __builtin_bit_cast(unsigned int, v);
}

__device__ __forceinline__ float fdot2(h2 a, h2 b, float c) {
#if __has_builtin(__builtin_amdgcn_fdot2)
    return __builtin_amdgcn_fdot2(a, b, c, false);
#else
    return c + (float)a[0] * (float)b[0] + (float)a[1] * (float)b[1];
#endif
}

#if __has_builtin(__builtin_amdgcn_update_dpp)
template <int CTRL>
__device__ __forceinline__ float dpp_add(float x) {
    int xi = __builtin_bit_cast(int, x);
    int t = __builtin_amdgcn_update_dpp(xi, xi, CTRL, 0xF, 0xF, false);
    return x + __builtin_bit_cast(float, t);
}
__device__ __forceinline__ float reduce16(float x) {
    x = dpp_add<0x128>(x);   // row_ror:8
    x = dpp_add<0x124>(x);   // row_ror:4
    x = dpp_add<0x122>(x);   // row_ror:2
    x = dpp_add<0x121>(x);   // row_ror:1
    return x;
}
#else
__device__ __forceinline__ float reduce16(float x) {
    x += __shfl_xor(x, 8); x += __shfl_xor(x, 4);
    x += __shfl_xor(x, 2); x += __shfl_xor(x, 1);
    return x;
}
#endif

struct alignas(16) H8 { h2 p[4]; };

// ---------------- Kernel 1: W1T (bf16 [512,128]) ----------------
__global__ __launch_bounds__(256) void build_w1t(const float* __restrict__ W1,
                                                 unsigned short* __restrict__ W1T) {
    int t2 = blockIdx.x * 256 + threadIdx.x;     // 0 .. 65535
    int j = t2 >> 7, k = t2 & 127;
    int row = (j < 256) ? k : (130 + k);
    int col = (j < 256) ? j : (j - 256);
    W1T[t2] = f2bf(W1[row * 256 + col]);
}

// ---------------- Kernel 2: fused F-build + P = F @ W1cat (+b1 on dst half) -> fp16 ----------------
__global__ __launch_bounds__(256) void p_gemm(const float* __restrict__ h,
                                              const float* __restrict__ cls,
                                              const unsigned short* __restrict__ W1T,
                                              const float* __restrict__ b1,
                                              _Float16* __restrict__ P) {
    __shared__ alignas(16) unsigned short As[64 * LDK];
    __shared__ alignas(16) unsigned short Bs[128 * LDK];
    float* Cs = (float*)&Bs[0];
    const int m0 = blockIdx.x * 64;
    const int t = threadIdx.x;

    #pragma unroll
    for (int it = 0; it < 4; ++it) {
        int chunk = t + it * 256;
        int r = chunk >> 4, c8 = chunk & 15;
        int row = m0 + r;
        unsigned int w0 = 0, w1 = 0, w2 = 0, w3 = 0;
        if (row < NN) {
            if (c8 < 15) {
                const float* hp = h + (size_t)row * H_DIM + c8 * 8;
                float4 v0 = *(const float4*)(hp);
                float4 v1 = *(const float4*)(hp + 4);
                w0 = pk2bf(v0.x, v0.y); w1 = pk2bf(v0.z, v0.w);
                w2 = pk2bf(v1.x, v1.y); w3 = pk2bf(v1.z, v1.w);
            } else {
                float4 v0 = *(const float4*)(h + (size_t)row * H_DIM + 120);
                float4 c = *(const float4*)(cls + (size_t)row * 4);
                float m = fmaxf(fmaxf(c.x, c.y), fmaxf(c.z, c.w));
                float e0 = __expf(c.x - m), e1 = __expf(c.y - m);
                float e2 = __expf(c.z - m), e3 = __expf(c.w - m);
                float inv = 1.0f / (e0 + e1 + e2 + e3);
                w0 = pk2bf(v0.x, v0.y); w1 = pk2bf(v0.z, v0.w);
                w2 = pk2bf(e0 * inv, e1 * inv); w3 = pk2bf(e2 * inv, e3 * inv);
            }
        }
        *(uint4*)(&As[r * LDK + c8 * 8]) = make_uint4(w0, w1, w2, w3);
    }
    __syncthreads();

    const int wave = t >> 6, lane = t & 63;
    const int wm = wave & 1, wn = wave >> 1;
    const int lm = lane & 15, quad = lane >> 4;

    bf16x8 afrag[4][2];
    #pragma unroll
    for (int s = 0; s < 4; ++s) {
        int k0 = s * 32 + quad * 8;
        #pragma unroll
        for (int mt = 0; mt < 2; ++mt)
            afrag[s][mt] = *(const bf16x8*)(&As[(wm * 32 + mt * 16 + lm) * LDK + k0]);
    }

    for (int cchunk = 0; cchunk < 4; ++cchunk) {
        const int n0 = cchunk * 128;
        if (cchunk) __syncthreads();
        #pragma unroll
        for (int it = 0; it < 8; ++it) {
            int chunk = t + it * 256;
            int r = chunk >> 4, c = chunk & 15;
            float4 v = *(const float4*)(W1T + (n0 + r) * 128 + c * 8);
            *(float4*)(&Bs[r * LDK + c * 8]) = v;
        }
        __syncthreads();

        f32x4 acc[2][4];
        #pragma unroll
        for (int mt = 0; mt < 2; ++mt)
            #pragma unroll
            for (int nt = 0; nt < 4; ++nt)
                acc[mt][nt] = (f32x4){0.f, 0.f, 0.f, 0.f};

        #pragma unroll
        for (int s = 0; s < 4; ++s) {
            int k0 = s * 32 + quad * 8;
            bf16x8 b[4];
            #pragma unroll
            for (int nt = 0; nt < 4; ++nt)
                b[nt] = *(const bf16x8*)(&Bs[(wn * 64 + nt * 16 + lm) * LDK + k0]);
            #pragma unroll
            for (int mt = 0; mt < 2; ++mt)
                #pragma unroll
                for (int nt = 0; nt < 4; ++nt)
                    acc[mt][nt] = __builtin_amdgcn_mfma_f32_16x16x32_bf16(afrag[s][mt], b[nt], acc[mt][nt], 0, 0, 0);
        }
        __syncthreads();

        #pragma unroll
        for (int mt = 0; mt < 2; ++mt)
            #pragma unroll
            for (int nt = 0; nt < 4; ++nt) {
                int col = wn * 64 + nt * 16 + lm;
                int rb  = wm * 32 + mt * 16 + quad * 4;
                #pragma unroll
                for (int r = 0; r < 4; ++r)
                    Cs[(rb + r) * CW + col] = acc[mt][nt][r];
            }
        __syncthreads();

        #pragma unroll
        for (int it = 0; it < 4; ++it) {
            int chunk = t + it * 256;
            int r = chunk >> 4, c8 = chunk & 15;
            float4 a = *(const float4*)(Cs + r * CW + c8 * 8);
            float4 b = *(const float4*)(Cs + r * CW + c8 * 8 + 4);
            if (n0 >= 256) {   // dst half: fold b1 (wave-uniform branch)
                int cb = n0 + c8 * 8 - 256;
                float4 ba = *(const float4*)(b1 + cb);
                float4 bb = *(const float4*)(b1 + cb + 4);
                a.x += ba.x; a.y += ba.y; a.z += ba.z; a.w += ba.w;
                b.x += bb.x; b.y += bb.y; b.z += bb.z; b.w += bb.w;
            }
            uint4 o = make_uint4(pk2h(a.x, a.y), pk2h(a.z, a.w),
                                 pk2h(b.x, b.y), pk2h(b.z, b.w));
            int row = m0 + r;
            if (row < NN)
                *(uint4*)(P + (size_t)row * PCOLS + n0 + c8 * 8) = o;
        }
    }
}

// ---------------- Kernel 3: edges — 16 lanes/edge, 4 edges/wave, DPP reductions ----------------
#define K3_BLOCKS 4096
#define K3_WAVES  (K3_BLOCKS * 4)      // 16384
#define K3_STRIDE (K3_WAVES * 4)       // 65536 edges per round
#define K3_ROUNDS 16                   // 16*65536 = 1,048,576 >= EE

struct EIdx { int s, d; float q0, q1; };

__device__ __forceinline__ EIdx load_idx(int eg, const int* __restrict__ src,
                                         const int* __restrict__ dst,
                                         const float* __restrict__ polar) {
    int ec = (eg < EE) ? eg : 0;
    EIdx r;
    r.s = src[ec]; r.d = dst[ec];
    float2 q = *(const float2*)(polar + 2 * ec);
    r.q0 = q.x; r.q1 = q.y;
    return r;
}

__device__ __forceinline__ void load_p(const _Float16* __restrict__ P, const EIdx& I,
                                       int il, H8* A) {
    const _Float16* ps = P + (size_t)I.s * PCOLS + il * 16;
    A[0] = *(const H8*)(ps);
    A[1] = *(const H8*)(ps + 8);
    const _Float16* pd = P + (size_t)I.d * PCOLS + 256 + il * 16;
    A[2] = *(const H8*)(pd);
    A[3] = *(const H8*)(pd + 8);
}

// __launch_bounds__(256, 4): 4 blocks/CU -> 16 waves/CU (same occupancy as the
// measured 50%) but VGPR ceiling 128 instead of the compiler-default 48 — lets
// the 48 VGPRs of fp16 constants stay register-resident instead of being
// re-loaded + re-converted every unrolled round (the round-4 VALU bloat).
__global__ __launch_bounds__(256, 4) void edge_kernel(const _Float16* __restrict__ P,
                                                   const int* __restrict__ src,
                                                   const int* __restrict__ dst,
                                                   const float* __restrict__ polar,
                                                   const float* __restrict__ W1,
                                                   const float* __restrict__ gamma,
                                                   const float* __restrict__ beta,
                                                   const float* __restrict__ W2,
                                                   const float* __restrict__ b2,
                                                   float* __restrict__ out) {
    const int lane = threadIdx.x & 63;
    const int il   = lane & 15;                  // lane within edge group
    const int g    = lane >> 4;                  // edge group 0..3
    const int wid  = blockIdx.x * 4 + (threadIdx.x >> 6);
    const int jb   = il * 16;                    // first element of this lane

    // Packed fp16 constants: 6 arrays x 8 half2 (b1 folded into P)
    h2 w0c[8], w1c[8], gc[8], bc[8], w2ac[8], w2bc[8];
    #pragma unroll
    for (int p = 0; p < 8; ++p) {
        int j = jb + 2 * p;
        float2 a0 = *(const float2*)(W1 + 128 * 256 + j);
        float2 a1 = *(const float2*)(W1 + 129 * 256 + j);
        float2 ag = *(const float2*)(gamma + j);
        float2 ae = *(const float2*)(beta + j);
        float4 w2v = *(const float4*)(W2 + 2 * j);
        w0c[p]  = (h2){(_Float16)a0.x, (_Float16)a0.y};
        w1c[p]  = (h2){(_Float16)a1.x, (_Float16)a1.y};
        gc[p]   = (h2){(_Float16)ag.x, (_Float16)ag.y};
        bc[p]   = (h2){(_Float16)ae.x, (_Float16)ae.y};
        w2ac[p] = (h2){(_Float16)w2v.x, (_Float16)w2v.z};
        w2bc[p] = (h2){(_Float16)w2v.y, (_Float16)w2v.w};
    }
    const float b20 = b2[0], b21 = b2[1];
    const h2 onep  = (h2){(_Float16)1.0f, (_Float16)1.0f};
    const h2 zerop = (h2){(_Float16)0.0f, (_Float16)0.0f};

    const int e0 = wid * 4 + g;

    EIdx I0 = load_idx(e0, src, dst, polar);
    H8 A[4]; load_p(P, I0, il, A);
    EIdx I1 = load_idx(e0 + K3_STRIDE, src, dst, polar);
    H8 B[4]; load_p(P, I1, il, B);

    #define EDGE_COMPUTE(Abuf, Ix, eg)                                        \
    {                                                                          \
        h2 p0 = (h2){(_Float16)(Ix).q0, (_Float16)(Ix).q0};                    \
        h2 p1 = (h2){(_Float16)(Ix).q1, (_Float16)(Ix).q1};                    \
        h2 z[8];                                                               \
        float sum = 0.f, ss = 0.f;                                             \
        _Pragma("unroll")                                                      \
        for (int p = 0; p < 8; ++p) {                                          \
            h2 pv = ((p < 4) ? (Abuf)[0].p[p] : (Abuf)[1].p[p - 4])            \
                  + ((p < 4) ? (Abuf)[2].p[p] : (Abuf)[3].p[p - 4]);           \
            h2 c = w0c[p] * p0 + w1c[p] * p1;                                  \
            z[p] = pv + c;                                                     \
            sum = fdot2(z[p], onep, sum);                                      \
            ss  = fdot2(z[p], z[p], ss);                                       \
        }                                                                      \
        sum = reduce16(sum); ss = reduce16(ss);                                \
        float mu   = sum * (1.0f / 256.0f);                                    \
        float var  = ss * (1.0f / 256.0f) - mu * mu;                           \
        float rstd = rsqrtf(var + 1e-5f);                                      \
        h2 muh = (h2){(_Float16)mu, (_Float16)mu};                             \
        h2 rsh = (h2){(_Float16)rstd, (_Float16)rstd};                         \
        float o0 = 0.f, o1 = 0.f;                                              \
        _Pragma("unroll")                                                      \
        for (int p = 0; p < 8; ++p) {                                          \
            h2 tt = (z[p] - muh) * rsh;                                        \
            h2 u = tt * gc[p] + bc[p];                                         \
            u = __builtin_elementwise_max(u, zerop);                           \
            o0 = fdot2(u, w2ac[p], o0);                                        \
            o1 = fdot2(u, w2bc[p], o1);                                        \
        }                                                                      \
        o0 = reduce16(o0); o1 = reduce16(o1);                                  \
        if (il == 0 && (eg) < EE)                                              \
            *(float2*)(out + 2 * (eg)) = make_float2(o0 + b20, o1 + b21);      \
    }

    #pragma unroll
    for (int r = 0; r < K3_ROUNDS; r += 2) {
        EDGE_COMPUTE(A, I0, e0 + r * K3_STRIDE);
        if (r + 2 < K3_ROUNDS) {
            I0 = load_idx(e0 + (r + 2) * K3_STRIDE, src, dst, polar);
            load_p(P, I0, il, A);
        }
        EDGE_COMPUTE(B, I1, e0 + (r + 1) * K3_STRIDE);
        if (r + 3 < K3_ROUNDS) {
            I1 = load_idx(e0 + (r + 3) * K3_STRIDE, src, dst, polar);
            load_p(P, I1, il, B);
        }
    }
    #undef EDGE_COMPUTE
}

extern "C" void kernel_launch(void* const* d_in, const int* in_sizes, int n_in,
                              void* d_out, int out_size, void* d_ws, size_t ws_size,
                              hipStream_t stream) {
    const float* h     = (const float*)d_in[0];
    const float* cls   = (const float*)d_in[1];
    const float* polar = (const float*)d_in[2];
    const int*   src   = (const int*)d_in[3];
    const int*   dst   = (const int*)d_in[4];
    const float* W1    = (const float*)d_in[5];
    const float* b1    = (const float*)d_in[6];
    const float* gamma = (const float*)d_in[7];
    const float* beta  = (const float*)d_in[8];
    const float* W2    = (const float*)d_in[9];
    const float* b2    = (const float*)d_in[10];
    float* out = (float*)d_out;

    char* ws = (char*)d_ws;
    _Float16*       P   = (_Float16*)ws;                      // N*512*2 = 102,400,000 B
    unsigned short* W1T = (unsigned short*)(ws + 102400000);  // 131,072 B

    build_w1t<<<256, 256, 0, stream>>>(W1, W1T);
    p_gemm<<<1563, 256, 0, stream>>>(h, cls, W1T, b1, P);
    edge_kernel<<<K3_BLOCKS, 256, 0, stream>>>(P, src, dst, polar, W1, gamma, beta, W2, b2, out);
}